// Round 2
// baseline (1782.590 us; speedup 1.0000x reference)
//
#include <hip/hip_runtime.h>
#include <hip/hip_bf16.h>

#define NN 100000
#define EE 1600000
#define GG 512
#define DIN 78
#define DF 32
#define DOUT 128
#define BN_EPS 1e-5f

#define NPB 32              // nodes per block in node-parallel kernels
#define NBLK_NODE 3125      // ceil(NN / NPB) == 100000/32 exactly

// ---------------------------------------------------------------- CSR build
__global__ __launch_bounds__(256) void k_hist(const int* __restrict__ dst, int* __restrict__ deg) {
    int e = blockIdx.x * 256 + threadIdx.x;
    if (e < EE) atomicAdd(&deg[dst[e]], 1);
}

__global__ __launch_bounds__(1024) void k_scan(int* __restrict__ cursor /*deg in, cursor out*/,
                                               int* __restrict__ row_ptr) {
    const int T = 1024;
    const int CH = (NN + T - 1) / T;   // 98
    __shared__ int sums[T];
    int t = threadIdx.x;
    int lo = t * CH;
    int hi = lo + CH; if (hi > NN) hi = NN;
    int s = 0;
    for (int i = lo; i < hi; ++i) s += cursor[i];
    sums[t] = s;
    __syncthreads();
    // Hillis-Steele inclusive scan
    for (int off = 1; off < T; off <<= 1) {
        int v = (t >= off) ? sums[t - off] : 0;
        __syncthreads();
        sums[t] += v;
        __syncthreads();
    }
    int run = (t == 0) ? 0 : sums[t - 1];  // exclusive prefix for this chunk
    for (int i = lo; i < hi; ++i) {
        int d = cursor[i];
        row_ptr[i] = run;
        cursor[i]  = run;    // cursor copy for the fill kernel
        run += d;
    }
    if (t == T - 1) row_ptr[NN] = run;
}

__global__ __launch_bounds__(256) void k_fill(const int* __restrict__ src, const int* __restrict__ dst,
                                              int* __restrict__ cursor, int* __restrict__ col) {
    int e = blockIdx.x * 256 + threadIdx.x;
    if (e < EE) {
        int pos = atomicAdd(&cursor[dst[e]], 1);
        col[pos] = src[e];
    }
}

// ---------------------------------------------------------------- layer kernels
// p = x @ w1   (layer 1, DIN=78 inputs, no BN)
__global__ __launch_bounds__(256) void k_proj_first(const float* __restrict__ x,
                                                    const float* __restrict__ w1,
                                                    float* __restrict__ p) {
    __shared__ float w[DIN][DF];
    __shared__ float hx[8][DIN];
    int tid = threadIdx.x;
    for (int i = tid; i < DIN * DF; i += 256) w[i / DF][i % DF] = w1[i];
    int row = tid >> 5, j = tid & 31;
    int base = blockIdx.x * NPB;
    __syncthreads();
    for (int it = 0; it < 4; ++it) {
        int n0 = base + it * 8;
        for (int i = tid; i < 8 * DIN; i += 256) {
            int rr = i / DIN, kk = i % DIN;
            int node = n0 + rr;
            hx[rr][kk] = (node < NN) ? x[node * DIN + kk] : 0.f;
        }
        __syncthreads();
        int node = n0 + row;
        if (node < NN) {
            float acc = 0.f;
            #pragma unroll
            for (int k = 0; k < DIN; ++k) acc += hx[row][k] * w[k][j];
            p[node * DF + j] = acc;
        }
        __syncthreads();
    }
}

// p = BN(r) @ w1   (hidden layers; BN of previous layer fused in)
__global__ __launch_bounds__(256) void k_proj_hidden(const float* __restrict__ r,
                                                     const float* __restrict__ w1_,
                                                     const float* __restrict__ stats,
                                                     const float* __restrict__ gamma,
                                                     const float* __restrict__ beta,
                                                     float* __restrict__ p) {
    __shared__ float w[DF][DF];
    __shared__ float h[8][DF];
    int tid = threadIdx.x;
    for (int i = tid; i < DF * DF; i += 256) w[i >> 5][i & 31] = w1_[i];
    int row = tid >> 5, j = tid & 31;
    float mu = stats[j], inv = stats[DF + j];
    float gj = gamma[j], bj = beta[j];
    int base = blockIdx.x * NPB;
    __syncthreads();
    for (int it = 0; it < 4; ++it) {
        int node = base + it * 8 + row;
        float hv = 0.f;
        if (node < NN) hv = gj * (r[node * DF + j] - mu) * inv + bj;
        h[row][j] = hv;
        __syncthreads();
        if (node < NN) {
            float acc = 0.f;
            #pragma unroll
            for (int k = 0; k < DF; ++k) acc += h[row][k] * w[k][j];
            p[node * DF + j] = acc;
        }
        __syncthreads();
    }
}

// agg + MLP-2 + relu + BN-stat partials
__global__ __launch_bounds__(256) void k_agg(const float* __restrict__ p,
                                             const int* __restrict__ row_ptr,
                                             const int* __restrict__ col,
                                             const float* __restrict__ b1,
                                             const float* __restrict__ w2_,
                                             const float* __restrict__ b2,
                                             float* __restrict__ r,
                                             float* __restrict__ partial) {
    __shared__ float w[DF][DF];
    __shared__ float a[8][DF];
    __shared__ float red[4][2][DF];
    int tid = threadIdx.x;
    for (int i = tid; i < DF * DF; i += 256) w[i >> 5][i & 31] = w2_[i];
    int row = tid >> 5, j = tid & 31;
    float b1j = b1[j], b2j = b2[j];
    float s1 = 0.f, s2 = 0.f;
    int base = blockIdx.x * NPB;
    __syncthreads();
    for (int it = 0; it < 4; ++it) {
        int node = base + it * 8 + row;
        float av = 0.f;
        if (node < NN) {
            float s = p[node * DF + j] + b1j;
            int e0 = row_ptr[node], e1 = row_ptr[node + 1];
            for (int e = e0; e < e1; ++e) {
                int srcn = col[e];
                s += p[srcn * DF + j];
            }
            av = fmaxf(s, 0.f);
        }
        a[row][j] = av;
        __syncthreads();
        if (node < NN) {
            float acc = b2j;
            #pragma unroll
            for (int k = 0; k < DF; ++k) acc += a[row][k] * w[k][j];
            float rv = fmaxf(acc, 0.f);
            r[node * DF + j] = rv;
            s1 += rv;
            s2 += rv * rv;
        }
        __syncthreads();
    }
    // reduce the 8 rows: lane+32 partner first, then across the 4 waves via LDS
    s1 += __shfl_down(s1, 32);
    s2 += __shfl_down(s2, 32);
    int wave = tid >> 6, lane = tid & 63;
    if (lane < 32) { red[wave][0][j] = s1; red[wave][1][j] = s2; }
    __syncthreads();
    if (tid < 32) {
        float t1 = red[0][0][j] + red[1][0][j] + red[2][0][j] + red[3][0][j];
        float t2 = red[0][1][j] + red[1][1][j] + red[2][1][j] + red[3][1][j];
        partial[blockIdx.x * 64 + j] = t1;
        partial[blockIdx.x * 64 + 32 + j] = t2;
    }
}

// reduce block partials -> mu, inv_std (deterministic, f64 accumulate)
__global__ __launch_bounds__(256) void k_finalize(const float* __restrict__ partial,
                                                  float* __restrict__ stats) {
    __shared__ double red[8][2][DF];
    int tid = threadIdx.x;
    int g = tid >> 5, j = tid & 31;
    double a1 = 0.0, a2 = 0.0;
    for (int b = g; b < NBLK_NODE; b += 8) {
        a1 += (double)partial[b * 64 + j];
        a2 += (double)partial[b * 64 + 32 + j];
    }
    red[g][0][j] = a1;
    red[g][1][j] = a2;
    __syncthreads();
    if (tid < 32) {
        double s1 = 0.0, s2 = 0.0;
        #pragma unroll
        for (int gg = 0; gg < 8; ++gg) { s1 += red[gg][0][j]; s2 += red[gg][1][j]; }
        double mu = s1 / (double)NN;
        double var = s2 / (double)NN - mu * mu;
        stats[j] = (float)mu;
        stats[DF + j] = (float)(1.0 / sqrt(var + (double)BN_EPS));
    }
}

// BN-apply (layer 5 stats) + global_add_pool via atomics
__global__ __launch_bounds__(256) void k_pool(const float* __restrict__ r,
                                              const float* __restrict__ stats,
                                              const float* __restrict__ gamma,
                                              const float* __restrict__ beta,
                                              const int* __restrict__ batch,
                                              float* __restrict__ pooled) {
    int t = blockIdx.x * 256 + threadIdx.x;
    if (t >= NN * DF) return;
    int node = t >> 5, j = t & 31;
    float val = gamma[j] * (r[t] - stats[j]) * stats[DF + j] + beta[j];
    atomicAdd(&pooled[batch[node] * DF + j], val);
}

__global__ __launch_bounds__(128) void k_fc(const float* __restrict__ pooled,
                                            const float* __restrict__ fc_w,
                                            const float* __restrict__ fc_b,
                                            float* __restrict__ out) {
    __shared__ float pl[DF];
    int g = blockIdx.x, j = threadIdx.x;
    if (j < DF) pl[j] = pooled[g * DF + j];
    __syncthreads();
    float acc = fc_b[j];
    #pragma unroll
    for (int k = 0; k < DF; ++k) acc += pl[k] * fc_w[k * DOUT + j];
    out[g * DOUT + j] = fmaxf(acc, 0.f);
}

// ---------------------------------------------------------------- host
extern "C" void kernel_launch(void* const* d_in, const int* in_sizes, int n_in,
                              void* d_out, int out_size, void* d_ws, size_t ws_size,
                              hipStream_t stream) {
    const float* x      = (const float*)d_in[0];
    const int*   eidx   = (const int*)d_in[1];
    const int*   batch  = (const int*)d_in[2];
    const float* w1_in  = (const float*)d_in[3];
    const float* b1_in  = (const float*)d_in[4];
    const float* w1_out = (const float*)d_in[5];
    const float* b1_out = (const float*)d_in[6];
    const float* wa     = (const float*)d_in[7];
    const float* ba     = (const float*)d_in[8];
    const float* wb     = (const float*)d_in[9];
    const float* bb     = (const float*)d_in[10];
    const float* gamma  = (const float*)d_in[11];
    const float* beta   = (const float*)d_in[12];
    const float* fc_w   = (const float*)d_in[13];
    const float* fc_b   = (const float*)d_in[14];
    float* out = (float*)d_out;

    const int* esrc = eidx;
    const int* edst = eidx + EE;

    // workspace carve-up
    float* W = (float*)d_ws;
    float* p       = W;                         // NN*DF
    float* r       = p + (size_t)NN * DF;       // NN*DF
    float* pooled  = r + (size_t)NN * DF;       // GG*DF
    float* stats   = pooled + (size_t)GG * DF;  // 64 (mu | inv)
    float* partial = stats + 64;                // NBLK_NODE*64
    int* row_ptr = (int*)(partial + (size_t)NBLK_NODE * 64);  // NN+1
    int* cursor  = row_ptr + (NN + 1);                        // NN
    int* col     = cursor + NN;                               // EE

    // ---- CSR build (same work every call) ----
    hipMemsetAsync(cursor, 0, sizeof(int) * NN, stream);
    k_hist<<<(EE + 255) / 256, 256, 0, stream>>>(edst, cursor);
    k_scan<<<1, 1024, 0, stream>>>(cursor, row_ptr);
    k_fill<<<(EE + 255) / 256, 256, 0, stream>>>(esrc, edst, cursor, col);

    // ---- layer 1 ----
    k_proj_first<<<NBLK_NODE, 256, 0, stream>>>(x, w1_in, p);
    k_agg<<<NBLK_NODE, 256, 0, stream>>>(p, row_ptr, col, b1_in, w1_out, b1_out, r, partial);
    k_finalize<<<1, 256, 0, stream>>>(partial, stats);

    // ---- layers 2..5 ----
    for (int i = 1; i < 5; ++i) {
        const float* w1_ = wa + (size_t)(i - 1) * DF * DF;
        const float* b1_ = ba + (size_t)(i - 1) * DF;
        const float* w2_ = wb + (size_t)(i - 1) * DF * DF;
        const float* b2_ = bb + (size_t)(i - 1) * DF;
        const float* g_  = gamma + (size_t)(i - 1) * DF;  // BN of previous layer
        const float* be_ = beta + (size_t)(i - 1) * DF;
        k_proj_hidden<<<NBLK_NODE, 256, 0, stream>>>(r, w1_, stats, g_, be_, p);
        k_agg<<<NBLK_NODE, 256, 0, stream>>>(p, row_ptr, col, b1_, w2_, b2_, r, partial);
        k_finalize<<<1, 256, 0, stream>>>(partial, stats);
    }

    // ---- pool (+ BN of layer 5) and FC ----
    hipMemsetAsync(pooled, 0, sizeof(float) * GG * DF, stream);
    k_pool<<<(NN * DF + 255) / 256, 256, 0, stream>>>(r, stats, gamma + 4 * DF, beta + 4 * DF,
                                                      batch, pooled);
    k_fc<<<GG, 128, 0, stream>>>(pooled, fc_w, fc_b, out);
}

// Round 4
// 1174.467 us; speedup vs baseline: 1.5178x; 1.5178x over previous
//
#include <hip/hip_runtime.h>
#include <hip/hip_bf16.h>

#define NN 100000
#define EE 1600000
#define GG 512
#define DIN 78
#define DF 32
#define DOUT 128
#define BN_EPS 1e-5f

#define NPB 32              // nodes per block in node-parallel kernels
#define NBLK_NODE 3125      // ceil(NN / NPB) == 100000/32 exactly

#define SCAN_C 256
#define SCAN_NB ((NN + SCAN_C - 1) / SCAN_C)   // 391

// ---------------------------------------------------------------- CSR build
__global__ __launch_bounds__(256) void k_hist(const int* __restrict__ dst, int* __restrict__ deg) {
    int e = blockIdx.x * 256 + threadIdx.x;
    if (e < EE) atomicAdd(&deg[dst[e]], 1);
}

// two-level scan: block reduce -> scan block sums -> block local scan + offset
__global__ __launch_bounds__(256) void k_scan1(const int* __restrict__ deg, int* __restrict__ bsum) {
    __shared__ int red[256];
    int t = threadIdx.x;
    int i = blockIdx.x * 256 + t;
    red[t] = (i < NN) ? deg[i] : 0;
    __syncthreads();
    for (int off = 128; off > 0; off >>= 1) {
        if (t < off) red[t] += red[t + off];
        __syncthreads();
    }
    if (t == 0) bsum[blockIdx.x] = red[0];
}

__global__ __launch_bounds__(1024) void k_scan2(int* __restrict__ bsum) {
    __shared__ int s[1024];
    int t = threadIdx.x;
    int v = (t < SCAN_NB) ? bsum[t] : 0;
    s[t] = v;
    __syncthreads();
    for (int off = 1; off < 1024; off <<= 1) {
        int u = (t >= off) ? s[t - off] : 0;
        __syncthreads();
        s[t] += u;
        __syncthreads();
    }
    if (t < SCAN_NB) bsum[t] = s[t] - v;  // exclusive prefix of block sums
}

__global__ __launch_bounds__(256) void k_scan3(const int* __restrict__ deg, const int* __restrict__ bsum,
                                               int* __restrict__ row_ptr, int* __restrict__ cursor) {
    __shared__ int s[256];
    int t = threadIdx.x;
    int i = blockIdx.x * 256 + t;
    int v = (i < NN) ? deg[i] : 0;
    s[t] = v;
    __syncthreads();
    for (int off = 1; off < 256; off <<= 1) {
        int u = (t >= off) ? s[t - off] : 0;
        __syncthreads();
        s[t] += u;
        __syncthreads();
    }
    int base = bsum[blockIdx.x];
    if (i < NN) {
        int ex = base + s[t] - v;
        row_ptr[i] = ex;
        cursor[i] = ex;
        if (i == NN - 1) row_ptr[NN] = base + s[t];
    }
}

__global__ __launch_bounds__(256) void k_fill(const int* __restrict__ src, const int* __restrict__ dst,
                                              int* __restrict__ cursor, int* __restrict__ col) {
    int e = blockIdx.x * 256 + threadIdx.x;
    if (e < EE) {
        int pos = atomicAdd(&cursor[dst[e]], 1);
        col[pos] = src[e];
    }
}

// ---------------------------------------------------------------- layer kernels
// p = x @ w1   (layer 1, DIN=78 inputs, no BN)
__global__ __launch_bounds__(256) void k_proj_first(const float* __restrict__ x,
                                                    const float* __restrict__ w1,
                                                    float* __restrict__ p) {
    __shared__ float w[DIN][DF];
    __shared__ float hx[8][DIN];
    int tid = threadIdx.x;
    for (int i = tid; i < DIN * DF; i += 256) w[i / DF][i % DF] = w1[i];
    int row = tid >> 5, j = tid & 31;
    int base = blockIdx.x * NPB;
    __syncthreads();
    for (int it = 0; it < 4; ++it) {
        int n0 = base + it * 8;
        for (int i = tid; i < 8 * DIN; i += 256) {
            int rr = i / DIN, kk = i % DIN;
            int node = n0 + rr;
            hx[rr][kk] = (node < NN) ? x[node * DIN + kk] : 0.f;
        }
        __syncthreads();
        int node = n0 + row;
        if (node < NN) {
            float acc = 0.f;
            #pragma unroll
            for (int k = 0; k < DIN; ++k) acc += hx[row][k] * w[k][j];
            p[node * DF + j] = acc;
        }
        __syncthreads();
    }
}

// p = BN(r) @ w1   (hidden layers; BN of previous layer fused in)
__global__ __launch_bounds__(256) void k_proj_hidden(const float* __restrict__ r,
                                                     const float* __restrict__ w1_,
                                                     const float* __restrict__ stats,
                                                     const float* __restrict__ gamma,
                                                     const float* __restrict__ beta,
                                                     float* __restrict__ p) {
    __shared__ float w[DF][DF];
    __shared__ float h[8][DF];
    int tid = threadIdx.x;
    for (int i = tid; i < DF * DF; i += 256) w[i >> 5][i & 31] = w1_[i];
    int row = tid >> 5, j = tid & 31;
    float mu = stats[j], inv = stats[DF + j];
    float gj = gamma[j], bj = beta[j];
    int base = blockIdx.x * NPB;
    __syncthreads();
    for (int it = 0; it < 4; ++it) {
        int node = base + it * 8 + row;
        float hv = 0.f;
        if (node < NN) hv = gj * (r[node * DF + j] - mu) * inv + bj;
        h[row][j] = hv;
        __syncthreads();
        if (node < NN) {
            float acc = 0.f;
            #pragma unroll
            for (int k = 0; k < DF; ++k) acc += h[row][k] * w[k][j];
            p[node * DF + j] = acc;
        }
        __syncthreads();
    }
}

// agg + MLP-2 + relu + BN-stat partials
__global__ __launch_bounds__(256) void k_agg(const float* __restrict__ p,
                                             const int* __restrict__ row_ptr,
                                             const int* __restrict__ col,
                                             const float* __restrict__ b1,
                                             const float* __restrict__ w2_,
                                             const float* __restrict__ b2,
                                             float* __restrict__ r,
                                             float* __restrict__ partial) {
    __shared__ float w[DF][DF];
    __shared__ float a[8][DF];
    __shared__ float red[4][2][DF];
    int tid = threadIdx.x;
    for (int i = tid; i < DF * DF; i += 256) w[i >> 5][i & 31] = w2_[i];
    int row = tid >> 5, j = tid & 31;
    float b1j = b1[j], b2j = b2[j];
    float s1 = 0.f, s2 = 0.f;
    int base = blockIdx.x * NPB;
    __syncthreads();
    for (int it = 0; it < 4; ++it) {
        int node = base + it * 8 + row;
        float av = 0.f;
        if (node < NN) {
            float s = p[node * DF + j] + b1j;
            int e0 = row_ptr[node], e1 = row_ptr[node + 1];
            for (int e = e0; e < e1; ++e) {
                int srcn = col[e];
                s += p[srcn * DF + j];
            }
            av = fmaxf(s, 0.f);
        }
        a[row][j] = av;
        __syncthreads();
        if (node < NN) {
            float acc = b2j;
            #pragma unroll
            for (int k = 0; k < DF; ++k) acc += a[row][k] * w[k][j];
            float rv = fmaxf(acc, 0.f);
            r[node * DF + j] = rv;
            s1 += rv;
            s2 += rv * rv;
        }
        __syncthreads();
    }
    s1 += __shfl_down(s1, 32);
    s2 += __shfl_down(s2, 32);
    int wave = tid >> 6, lane = tid & 63;
    if (lane < 32) { red[wave][0][j] = s1; red[wave][1][j] = s2; }
    __syncthreads();
    if (tid < 32) {
        float t1 = red[0][0][j] + red[1][0][j] + red[2][0][j] + red[3][0][j];
        float t2 = red[0][1][j] + red[1][1][j] + red[2][1][j] + red[3][1][j];
        partial[blockIdx.x * 64 + j] = t1;
        partial[blockIdx.x * 64 + 32 + j] = t2;
    }
}

// reduce block partials -> mu, inv_std (deterministic, f64 accumulate)
__global__ __launch_bounds__(1024) void k_finalize(const float* __restrict__ partial,
                                                   float* __restrict__ stats) {
    __shared__ double red[32][2][DF];
    int tid = threadIdx.x;
    int g = tid >> 5, j = tid & 31;
    double a1 = 0.0, a2 = 0.0;
    for (int b = g; b < NBLK_NODE; b += 32) {
        a1 += (double)partial[b * 64 + j];
        a2 += (double)partial[b * 64 + 32 + j];
    }
    red[g][0][j] = a1;
    red[g][1][j] = a2;
    __syncthreads();
    if (tid < 32) {
        double s1 = 0.0, s2 = 0.0;
        #pragma unroll
        for (int gg = 0; gg < 32; ++gg) { s1 += red[gg][0][j]; s2 += red[gg][1][j]; }
        double mu = s1 / (double)NN;
        double var = s2 / (double)NN - mu * mu;
        stats[j] = (float)mu;
        stats[DF + j] = (float)(1.0 / sqrt(var + (double)BN_EPS));
    }
}

// BN-apply (layer 5 stats) + global_add_pool via atomics
__global__ __launch_bounds__(256) void k_pool(const float* __restrict__ r,
                                              const float* __restrict__ stats,
                                              const float* __restrict__ gamma,
                                              const float* __restrict__ beta,
                                              const int* __restrict__ batch,
                                              float* __restrict__ pooled) {
    int t = blockIdx.x * 256 + threadIdx.x;
    if (t >= NN * DF) return;
    int node = t >> 5, j = t & 31;
    float val = gamma[j] * (r[t] - stats[j]) * stats[DF + j] + beta[j];
    atomicAdd(&pooled[batch[node] * DF + j], val);
}

__global__ __launch_bounds__(128) void k_fc(const float* __restrict__ pooled,
                                            const float* __restrict__ fc_w,
                                            const float* __restrict__ fc_b,
                                            float* __restrict__ out) {
    __shared__ float pl[DF];
    int g = blockIdx.x, j = threadIdx.x;
    if (j < DF) pl[j] = pooled[g * DF + j];
    __syncthreads();
    float acc = fc_b[j];
    #pragma unroll
    for (int k = 0; k < DF; ++k) acc += pl[k] * fc_w[k * DOUT + j];
    out[g * DOUT + j] = fmaxf(acc, 0.f);
}

// ---------------------------------------------------------------- host
extern "C" void kernel_launch(void* const* d_in, const int* in_sizes, int n_in,
                              void* d_out, int out_size, void* d_ws, size_t ws_size,
                              hipStream_t stream) {
    const float* x      = (const float*)d_in[0];
    const int*   eidx   = (const int*)d_in[1];
    const int*   batch  = (const int*)d_in[2];
    const float* w1_in  = (const float*)d_in[3];
    const float* b1_in  = (const float*)d_in[4];
    const float* w1_out = (const float*)d_in[5];
    const float* b1_out = (const float*)d_in[6];
    const float* wa     = (const float*)d_in[7];
    const float* ba     = (const float*)d_in[8];
    const float* wb     = (const float*)d_in[9];
    const float* bb     = (const float*)d_in[10];
    const float* gamma  = (const float*)d_in[11];
    const float* beta   = (const float*)d_in[12];
    const float* fc_w   = (const float*)d_in[13];
    const float* fc_b   = (const float*)d_in[14];
    float* out = (float*)d_out;

    const int* esrc = eidx;
    const int* edst = eidx + EE;

    // workspace carve-up
    float* W = (float*)d_ws;
    float* p       = W;                         // NN*DF
    float* r       = p + (size_t)NN * DF;       // NN*DF
    float* pooled  = r + (size_t)NN * DF;       // GG*DF
    float* stats   = pooled + (size_t)GG * DF;  // 64 (mu | inv)
    float* partial = stats + 64;                // NBLK_NODE*64
    int* row_ptr = (int*)(partial + (size_t)NBLK_NODE * 64);  // NN+1
    int* cursor  = row_ptr + (NN + 1);                        // NN
    int* deg     = cursor + NN;                               // NN
    int* bsum    = deg + NN;                                  // SCAN_NB
    int* col     = bsum + SCAN_NB;                            // EE

    // ---- CSR build (same work every call) ----
    hipMemsetAsync(deg, 0, sizeof(int) * NN, stream);
    k_hist<<<(EE + 255) / 256, 256, 0, stream>>>(edst, deg);
    k_scan1<<<SCAN_NB, 256, 0, stream>>>(deg, bsum);
    k_scan2<<<1, 1024, 0, stream>>>(bsum);
    k_scan3<<<SCAN_NB, 256, 0, stream>>>(deg, bsum, row_ptr, cursor);
    k_fill<<<(EE + 255) / 256, 256, 0, stream>>>(esrc, edst, cursor, col);

    // ---- layer 1 ----
    k_proj_first<<<NBLK_NODE, 256, 0, stream>>>(x, w1_in, p);
    k_agg<<<NBLK_NODE, 256, 0, stream>>>(p, row_ptr, col, b1_in, w1_out, b1_out, r, partial);
    k_finalize<<<1, 1024, 0, stream>>>(partial, stats);

    // ---- layers 2..5 ----
    for (int i = 1; i < 5; ++i) {
        const float* w1_ = wa + (size_t)(i - 1) * DF * DF;
        const float* b1_ = ba + (size_t)(i - 1) * DF;
        const float* w2_ = wb + (size_t)(i - 1) * DF * DF;
        const float* b2_ = bb + (size_t)(i - 1) * DF;
        const float* g_  = gamma + (size_t)(i - 1) * DF;  // BN of previous layer
        const float* be_ = beta + (size_t)(i - 1) * DF;
        k_proj_hidden<<<NBLK_NODE, 256, 0, stream>>>(r, w1_, stats, g_, be_, p);
        k_agg<<<NBLK_NODE, 256, 0, stream>>>(p, row_ptr, col, b1_, w2_, b2_, r, partial);
        k_finalize<<<1, 1024, 0, stream>>>(partial, stats);
    }

    // ---- pool (+ BN of layer 5) and FC ----
    hipMemsetAsync(pooled, 0, sizeof(float) * GG * DF, stream);
    k_pool<<<(NN * DF + 255) / 256, 256, 0, stream>>>(r, stats, gamma + 4 * DF, beta + 4 * DF,
                                                      batch, pooled);
    k_fc<<<GG, 128, 0, stream>>>(pooled, fc_w, fc_b, out);
}

// Round 5
// 893.557 us; speedup vs baseline: 1.9949x; 1.3144x over previous
//
#include <hip/hip_runtime.h>
#include <hip/hip_bf16.h>

#define NN 100000
#define EE 1600000
#define GG 512
#define DIN 78
#define DF 32
#define DOUT 128
#define BN_EPS 1e-5f

#define NBLK_NODE 3125      // NN / 32 exactly

#define SCAN_C 256
#define SCAN_NB ((NN + SCAN_C - 1) / SCAN_C)   // 391

// ---------------------------------------------------------------- CSR build
__global__ __launch_bounds__(256) void k_hist(const int* __restrict__ dst, int* __restrict__ deg) {
    int e = blockIdx.x * 256 + threadIdx.x;
    if (e < EE) atomicAdd(&deg[dst[e]], 1);
}

__global__ __launch_bounds__(256) void k_scan1(const int* __restrict__ deg, int* __restrict__ bsum) {
    __shared__ int red[256];
    int t = threadIdx.x;
    int i = blockIdx.x * 256 + t;
    red[t] = (i < NN) ? deg[i] : 0;
    __syncthreads();
    for (int off = 128; off > 0; off >>= 1) {
        if (t < off) red[t] += red[t + off];
        __syncthreads();
    }
    if (t == 0) bsum[blockIdx.x] = red[0];
}

__global__ __launch_bounds__(1024) void k_scan2(int* __restrict__ bsum) {
    __shared__ int s[1024];
    int t = threadIdx.x;
    int v = (t < SCAN_NB) ? bsum[t] : 0;
    s[t] = v;
    __syncthreads();
    for (int off = 1; off < 1024; off <<= 1) {
        int u = (t >= off) ? s[t - off] : 0;
        __syncthreads();
        s[t] += u;
        __syncthreads();
    }
    if (t < SCAN_NB) bsum[t] = s[t] - v;  // exclusive prefix of block sums
}

__global__ __launch_bounds__(256) void k_scan3(const int* __restrict__ deg, const int* __restrict__ bsum,
                                               int* __restrict__ row_ptr, int* __restrict__ cursor) {
    __shared__ int s[256];
    int t = threadIdx.x;
    int i = blockIdx.x * 256 + t;
    int v = (i < NN) ? deg[i] : 0;
    s[t] = v;
    __syncthreads();
    for (int off = 1; off < 256; off <<= 1) {
        int u = (t >= off) ? s[t - off] : 0;
        __syncthreads();
        s[t] += u;
        __syncthreads();
    }
    int base = bsum[blockIdx.x];
    if (i < NN) {
        int ex = base + s[t] - v;
        row_ptr[i] = ex;
        cursor[i] = ex;
        if (i == NN - 1) row_ptr[NN] = base + s[t];
    }
}

__global__ __launch_bounds__(256) void k_fill(const int* __restrict__ src, const int* __restrict__ dst,
                                              int* __restrict__ cursor, int* __restrict__ col) {
    int e = blockIdx.x * 256 + threadIdx.x;
    if (e < EE) {
        int pos = atomicAdd(&cursor[dst[e]], 1);
        col[pos] = src[e];
    }
}

// ---------------------------------------------------------------- layer kernels
// p = x @ w1  (layer 1, DIN=78, no BN).  32 nodes/block, single sync.
__global__ __launch_bounds__(256) void k_proj_first(const float* __restrict__ x,
                                                    const float* __restrict__ w1,
                                                    float* __restrict__ p) {
    __shared__ float w[DIN][DF];
    __shared__ float hx[32][DIN];
    int tid = threadIdx.x;
    for (int i = tid; i < DIN * DF; i += 256) w[i >> 5][i & 31] = w1[i];
    int base = blockIdx.x * 32;
    // coalesced: global index base*78 + i is linear
    for (int i = tid; i < 32 * DIN; i += 256) hx[i / DIN][i % DIN] = x[base * DIN + i];
    __syncthreads();
    int j = tid & 31;
    #pragma unroll
    for (int it = 0; it < 4; ++it) {
        int rown = (tid >> 5) + 8 * it;
        float acc = 0.f;
        #pragma unroll
        for (int k = 0; k < DIN; ++k) acc += hx[rown][k] * w[k][j];
        p[(base + rown) * DF + j] = acc;
    }
}

// p = BN(r) @ w1  (hidden layers).  32 nodes/block, float4 loads, single sync.
__global__ __launch_bounds__(256) void k_proj_hidden(const float* __restrict__ r,
                                                     const float* __restrict__ w1_,
                                                     const float* __restrict__ stats,
                                                     const float* __restrict__ gamma,
                                                     const float* __restrict__ beta,
                                                     float* __restrict__ p) {
    __shared__ float w[DF][DF];
    __shared__ float h[32][DF + 1];
    int tid = threadIdx.x;
    for (int i = tid; i < DF * DF; i += 256) w[i >> 5][i & 31] = w1_[i];
    int grp = tid >> 3, c = tid & 7;
    int node = blockIdx.x * 32 + grp;
    float4 rv  = ((const float4*)r)[node * 8 + c];
    float4 muv = ((const float4*)stats)[c];
    float4 ivv = ((const float4*)(stats + DF))[c];
    float4 gv  = ((const float4*)gamma)[c];
    float4 bv  = ((const float4*)beta)[c];
    h[grp][4 * c + 0] = gv.x * (rv.x - muv.x) * ivv.x + bv.x;
    h[grp][4 * c + 1] = gv.y * (rv.y - muv.y) * ivv.y + bv.y;
    h[grp][4 * c + 2] = gv.z * (rv.z - muv.z) * ivv.z + bv.z;
    h[grp][4 * c + 3] = gv.w * (rv.w - muv.w) * ivv.w + bv.w;
    __syncthreads();
    int j = tid & 31;
    #pragma unroll
    for (int it = 0; it < 4; ++it) {
        int rown = (tid >> 5) + 8 * it;
        float acc = 0.f;
        #pragma unroll
        for (int k = 0; k < DF; ++k) acc += h[rown][k] * w[k][j];
        p[(blockIdx.x * 32 + rown) * DF + j] = acc;
    }
}

// agg (float4 gather) + MLP-2 + relu + BN-stat partials.  32 nodes/block.
__global__ __launch_bounds__(256) void k_agg(const float* __restrict__ p,
                                             const int* __restrict__ row_ptr,
                                             const int* __restrict__ col,
                                             const float* __restrict__ b1,
                                             const float* __restrict__ w2_,
                                             const float* __restrict__ b2,
                                             float* __restrict__ r,
                                             float* __restrict__ partial) {
    __shared__ float w[DF][DF];
    __shared__ float a[32][DF + 1];
    __shared__ float red[4][2][DF];
    int tid = threadIdx.x;
    for (int i = tid; i < DF * DF; i += 256) w[i >> 5][i & 31] = w2_[i];
    int grp = tid >> 3, c = tid & 7;
    int node = blockIdx.x * 32 + grp;
    const float4* p4 = (const float4*)p;
    float4 acc = p4[node * 8 + c];         // self term
    int e0 = row_ptr[node], e1 = row_ptr[node + 1];
    for (int e = e0; e < e1; ++e) {
        int srcn = col[e];
        float4 v = p4[srcn * 8 + c];
        acc.x += v.x; acc.y += v.y; acc.z += v.z; acc.w += v.w;
    }
    float4 b1v = ((const float4*)b1)[c];
    a[grp][4 * c + 0] = fmaxf(acc.x + b1v.x, 0.f);
    a[grp][4 * c + 1] = fmaxf(acc.y + b1v.y, 0.f);
    a[grp][4 * c + 2] = fmaxf(acc.z + b1v.z, 0.f);
    a[grp][4 * c + 3] = fmaxf(acc.w + b1v.w, 0.f);
    __syncthreads();
    int j = tid & 31;
    float b2j = b2[j];
    float s1 = 0.f, s2 = 0.f;
    #pragma unroll
    for (int it = 0; it < 4; ++it) {
        int rown = (tid >> 5) + 8 * it;
        float accm = b2j;
        #pragma unroll
        for (int k = 0; k < DF; ++k) accm += a[rown][k] * w[k][j];
        float rv = fmaxf(accm, 0.f);
        r[(blockIdx.x * 32 + rown) * DF + j] = rv;
        s1 += rv;
        s2 += rv * rv;
    }
    s1 += __shfl_down(s1, 32);
    s2 += __shfl_down(s2, 32);
    int wave = tid >> 6, lane = tid & 63;
    if (lane < 32) { red[wave][0][j] = s1; red[wave][1][j] = s2; }
    __syncthreads();
    if (tid < 32) {
        float t1 = red[0][0][j] + red[1][0][j] + red[2][0][j] + red[3][0][j];
        float t2 = red[0][1][j] + red[1][1][j] + red[2][1][j] + red[3][1][j];
        partial[blockIdx.x * 64 + j] = t1;
        partial[blockIdx.x * 64 + 32 + j] = t2;
    }
}

// reduce block partials -> mu, inv_std (deterministic, f64 accumulate)
__global__ __launch_bounds__(1024) void k_finalize(const float* __restrict__ partial,
                                                   float* __restrict__ stats) {
    __shared__ double red[32][2][DF];
    int tid = threadIdx.x;
    int g = tid >> 5, j = tid & 31;
    double a1 = 0.0, a2 = 0.0;
    for (int b = g; b < NBLK_NODE; b += 32) {
        a1 += (double)partial[b * 64 + j];
        a2 += (double)partial[b * 64 + 32 + j];
    }
    red[g][0][j] = a1;
    red[g][1][j] = a2;
    __syncthreads();
    if (tid < 32) {
        double s1 = 0.0, s2 = 0.0;
        #pragma unroll
        for (int gg = 0; gg < 32; ++gg) { s1 += red[gg][0][j]; s2 += red[gg][1][j]; }
        double mu = s1 / (double)NN;
        double var = s2 / (double)NN - mu * mu;
        stats[j] = (float)mu;
        stats[DF + j] = (float)(1.0 / sqrt(var + (double)BN_EPS));
    }
}

// BN-apply (layer-5 stats) + global_add_pool; run-length accumulate over
// 8 consecutive nodes (batch is sorted) -> ~8x fewer atomics.
__global__ __launch_bounds__(256) void k_pool(const float* __restrict__ r,
                                              const float* __restrict__ stats,
                                              const float* __restrict__ gamma,
                                              const float* __restrict__ beta,
                                              const int* __restrict__ batch,
                                              float* __restrict__ pooled) {
    int t = blockIdx.x * 256 + threadIdx.x;
    int nodeBase = (t >> 5) * 8;
    if (nodeBase >= NN) return;
    int j = t & 31;
    float mu = stats[j], inv = stats[DF + j];
    float gj = gamma[j], bj = beta[j];
    float accp = 0.f;
    int curg = batch[nodeBase];
    #pragma unroll
    for (int k = 0; k < 8; ++k) {
        int n = nodeBase + k;
        int g = batch[n];
        float val = gj * (r[n * DF + j] - mu) * inv + bj;
        if (g != curg) { atomicAdd(&pooled[curg * DF + j], accp); accp = 0.f; curg = g; }
        accp += val;
    }
    atomicAdd(&pooled[curg * DF + j], accp);
}

__global__ __launch_bounds__(128) void k_fc(const float* __restrict__ pooled,
                                            const float* __restrict__ fc_w,
                                            const float* __restrict__ fc_b,
                                            float* __restrict__ out) {
    __shared__ float pl[DF];
    int g = blockIdx.x, j = threadIdx.x;
    if (j < DF) pl[j] = pooled[g * DF + j];
    __syncthreads();
    float acc = fc_b[j];
    #pragma unroll
    for (int k = 0; k < DF; ++k) acc += pl[k] * fc_w[k * DOUT + j];
    out[g * DOUT + j] = fmaxf(acc, 0.f);
}

// ---------------------------------------------------------------- host
extern "C" void kernel_launch(void* const* d_in, const int* in_sizes, int n_in,
                              void* d_out, int out_size, void* d_ws, size_t ws_size,
                              hipStream_t stream) {
    const float* x      = (const float*)d_in[0];
    const int*   eidx   = (const int*)d_in[1];
    const int*   batch  = (const int*)d_in[2];
    const float* w1_in  = (const float*)d_in[3];
    const float* b1_in  = (const float*)d_in[4];
    const float* w1_out = (const float*)d_in[5];
    const float* b1_out = (const float*)d_in[6];
    const float* wa     = (const float*)d_in[7];
    const float* ba     = (const float*)d_in[8];
    const float* wb     = (const float*)d_in[9];
    const float* bb     = (const float*)d_in[10];
    const float* gamma  = (const float*)d_in[11];
    const float* beta   = (const float*)d_in[12];
    const float* fc_w   = (const float*)d_in[13];
    const float* fc_b   = (const float*)d_in[14];
    float* out = (float*)d_out;

    const int* esrc = eidx;
    const int* edst = eidx + EE;

    // workspace carve-up
    float* W = (float*)d_ws;
    float* p       = W;                         // NN*DF
    float* r       = p + (size_t)NN * DF;       // NN*DF
    float* pooled  = r + (size_t)NN * DF;       // GG*DF
    float* stats   = pooled + (size_t)GG * DF;  // 64 (mu | inv)
    float* partial = stats + 64;                // NBLK_NODE*64
    int* row_ptr = (int*)(partial + (size_t)NBLK_NODE * 64);  // NN+1
    int* cursor  = row_ptr + (NN + 1);                        // NN
    int* deg     = cursor + NN;                               // NN
    int* bsum    = deg + NN;                                  // SCAN_NB
    int* col     = bsum + SCAN_NB;                            // EE

    // ---- CSR build (same work every call) ----
    hipMemsetAsync(deg, 0, sizeof(int) * NN, stream);
    k_hist<<<(EE + 255) / 256, 256, 0, stream>>>(edst, deg);
    k_scan1<<<SCAN_NB, 256, 0, stream>>>(deg, bsum);
    k_scan2<<<1, 1024, 0, stream>>>(bsum);
    k_scan3<<<SCAN_NB, 256, 0, stream>>>(deg, bsum, row_ptr, cursor);
    k_fill<<<(EE + 255) / 256, 256, 0, stream>>>(esrc, edst, cursor, col);

    // ---- layer 1 ----
    k_proj_first<<<NBLK_NODE, 256, 0, stream>>>(x, w1_in, p);
    k_agg<<<NBLK_NODE, 256, 0, stream>>>(p, row_ptr, col, b1_in, w1_out, b1_out, r, partial);
    k_finalize<<<1, 1024, 0, stream>>>(partial, stats);

    // ---- layers 2..5 ----
    for (int i = 1; i < 5; ++i) {
        const float* w1_ = wa + (size_t)(i - 1) * DF * DF;
        const float* b1_ = ba + (size_t)(i - 1) * DF;
        const float* w2_ = wb + (size_t)(i - 1) * DF * DF;
        const float* b2_ = bb + (size_t)(i - 1) * DF;
        const float* g_  = gamma + (size_t)(i - 1) * DF;  // BN of previous layer
        const float* be_ = beta + (size_t)(i - 1) * DF;
        k_proj_hidden<<<NBLK_NODE, 256, 0, stream>>>(r, w1_, stats, g_, be_, p);
        k_agg<<<NBLK_NODE, 256, 0, stream>>>(p, row_ptr, col, b1_, w2_, b2_, r, partial);
        k_finalize<<<1, 1024, 0, stream>>>(partial, stats);
    }

    // ---- pool (+ BN of layer 5) and FC ----
    hipMemsetAsync(pooled, 0, sizeof(float) * GG * DF, stream);
    k_pool<<<((NN / 8) * 32 + 255) / 256, 256, 0, stream>>>(r, stats, gamma + 4 * DF, beta + 4 * DF,
                                                            batch, pooled);
    k_fc<<<GG, 128, 0, stream>>>(pooled, fc_w, fc_b, out);
}

// Round 6
// 835.432 us; speedup vs baseline: 2.1337x; 1.0696x over previous
//
#include <hip/hip_runtime.h>
#include <hip/hip_bf16.h>

#define NN 100000
#define EE 1600000
#define GG 512
#define DIN 78
#define DF 32
#define DOUT 128
#define BN_EPS 1e-5f

#define NBLK_NODE 3125      // NN / 32 exactly

#define BSH 9               // 512 nodes per bucket
#define NBUCK 196           // ceil(100000 / 512)
#define SCB 256             // scatter blocks
#define EPB (EE / SCB)      // 6250 edges per scatter block

// ---------------------------------------------------------------- CSR build (bucketed)
// Pass 1: per-(block) histogram over 196 dst-buckets
__global__ __launch_bounds__(256) void k_bhist(const int* __restrict__ dst, int* __restrict__ hist_g) {
    __shared__ int hist[NBUCK];
    int tid = threadIdx.x, blk = blockIdx.x;
    if (tid < NBUCK) hist[tid] = 0;
    __syncthreads();
    int start = blk * EPB, end = start + EPB;
    for (int i = start + tid; i < end; i += 256) atomicAdd(&hist[dst[i] >> BSH], 1);
    __syncthreads();
    if (tid < NBUCK) hist_g[tid * SCB + blk] = hist[tid];
}

// Pass 2: one block: bucket totals -> bucket bases -> absolute per-(bucket,block) offsets
__global__ __launch_bounds__(256) void k_bscan(int* __restrict__ hist_g, int* __restrict__ bbase) {
    __shared__ int tot[256];
    int t = threadIdx.x;
    int total = 0;
    if (t < NBUCK)
        for (int blk = 0; blk < SCB; ++blk) total += hist_g[t * SCB + blk];
    tot[t] = (t < NBUCK) ? total : 0;
    __syncthreads();
    for (int off = 1; off < 256; off <<= 1) {
        int u = (t >= off) ? tot[t - off] : 0;
        __syncthreads();
        tot[t] += u;
        __syncthreads();
    }
    int excl = tot[t] - total;  // exclusive prefix (total only valid t<NBUCK; else total=0 ok)
    if (t < NBUCK) {
        bbase[t] = excl;
        int run = excl;
        for (int blk = 0; blk < SCB; ++blk) {
            int h = hist_g[t * SCB + blk];
            hist_g[t * SCB + blk] = run;
            run += h;
        }
    }
    if (t == 0) bbase[NBUCK] = EE;
}

// Pass 3: scatter (src,dst) pairs into bucket-contiguous regions
__global__ __launch_bounds__(256) void k_bscatter(const int* __restrict__ src, const int* __restrict__ dst,
                                                  const int* __restrict__ hist_g, int2* __restrict__ pairs) {
    __shared__ int base_l[NBUCK];
    __shared__ int cnt[NBUCK];
    int tid = threadIdx.x, blk = blockIdx.x;
    if (tid < NBUCK) { base_l[tid] = hist_g[tid * SCB + blk]; cnt[tid] = 0; }
    __syncthreads();
    int start = blk * EPB, end = start + EPB;
    for (int i = start + tid; i < end; i += 256) {
        int d = dst[i], s = src[i];
        int b = d >> BSH;
        int rk = atomicAdd(&cnt[b], 1);
        pairs[base_l[b] + rk] = make_int2(s, d);
    }
}

// Pass 4: per bucket: per-node count + scan -> row_ptr; then fill col locally
__global__ __launch_bounds__(256) void k_bfill(const int2* __restrict__ pairs, const int* __restrict__ bbase,
                                               int* __restrict__ row_ptr, int* __restrict__ col) {
    __shared__ int cnt[512];
    __shared__ int excl[512];
    __shared__ int ps[256];
    int tid = threadIdx.x, b = blockIdx.x;
    int base = bbase[b];
    int cntb = bbase[b + 1] - base;
    int nbase = b << BSH;
    int nloc = NN - nbase; if (nloc > 512) nloc = 512;
    cnt[tid] = 0; cnt[tid + 256] = 0;
    __syncthreads();
    for (int i = tid; i < cntb; i += 256) atomicAdd(&cnt[pairs[base + i].y - nbase], 1);
    __syncthreads();
    int a0 = cnt[2 * tid], a1 = cnt[2 * tid + 1];
    ps[tid] = a0 + a1;
    __syncthreads();
    for (int off = 1; off < 256; off <<= 1) {
        int u = (tid >= off) ? ps[tid - off] : 0;
        __syncthreads();
        ps[tid] += u;
        __syncthreads();
    }
    int pexcl = ps[tid] - (a0 + a1);
    excl[2 * tid] = pexcl;
    excl[2 * tid + 1] = pexcl + a0;
    __syncthreads();
    for (int i = tid; i < nloc; i += 256) row_ptr[nbase + i] = base + excl[i];
    if (b == 0 && tid == 0) row_ptr[NN] = EE;
    __syncthreads();
    for (int i = tid; i < cntb; i += 256) {
        int2 pr = pairs[base + i];
        int lp = atomicAdd(&excl[pr.y - nbase], 1);
        col[base + lp] = pr.x;
    }
}

// ---------------------------------------------------------------- layer kernels
// p = x @ w1  (layer 1, DIN=78, no BN).  32 nodes/block, single sync.
__global__ __launch_bounds__(256) void k_proj_first(const float* __restrict__ x,
                                                    const float* __restrict__ w1,
                                                    float* __restrict__ p) {
    __shared__ float w[DIN][DF];
    __shared__ float hx[32][DIN];
    int tid = threadIdx.x;
    for (int i = tid; i < DIN * DF; i += 256) w[i >> 5][i & 31] = w1[i];
    int base = blockIdx.x * 32;
    for (int i = tid; i < 32 * DIN; i += 256) hx[i / DIN][i % DIN] = x[base * DIN + i];
    __syncthreads();
    int j = tid & 31;
    #pragma unroll
    for (int it = 0; it < 4; ++it) {
        int rown = (tid >> 5) + 8 * it;
        float acc = 0.f;
        #pragma unroll
        for (int k = 0; k < DIN; ++k) acc += hx[rown][k] * w[k][j];
        p[(base + rown) * DF + j] = acc;
    }
}

// p = BN(r) @ w1  (hidden layers).  BN stats computed inline from raw sums.
__global__ __launch_bounds__(256) void k_proj_hidden(const float* __restrict__ r,
                                                     const float* __restrict__ w1_,
                                                     const float* __restrict__ statsL,
                                                     const float* __restrict__ gamma,
                                                     const float* __restrict__ beta,
                                                     float* __restrict__ p) {
    __shared__ float w[DF][DF];
    __shared__ float h[32][DF + 1];
    int tid = threadIdx.x;
    for (int i = tid; i < DF * DF; i += 256) w[i >> 5][i & 31] = w1_[i];
    int grp = tid >> 3, c = tid & 7;
    int node = blockIdx.x * 32 + grp;
    const float invN = 1.0f / (float)NN;
    float4 s1v = ((const float4*)statsL)[c];
    float4 s2v = ((const float4*)(statsL + DF))[c];
    float4 gv  = ((const float4*)gamma)[c];
    float4 bv  = ((const float4*)beta)[c];
    float4 rv  = ((const float4*)r)[node * 8 + c];
    float mux = s1v.x * invN, muy = s1v.y * invN, muz = s1v.z * invN, muw = s1v.w * invN;
    float ivx = rsqrtf(s2v.x * invN - mux * mux + BN_EPS);
    float ivy = rsqrtf(s2v.y * invN - muy * muy + BN_EPS);
    float ivz = rsqrtf(s2v.z * invN - muz * muz + BN_EPS);
    float ivw = rsqrtf(s2v.w * invN - muw * muw + BN_EPS);
    h[grp][4 * c + 0] = gv.x * (rv.x - mux) * ivx + bv.x;
    h[grp][4 * c + 1] = gv.y * (rv.y - muy) * ivy + bv.y;
    h[grp][4 * c + 2] = gv.z * (rv.z - muz) * ivz + bv.z;
    h[grp][4 * c + 3] = gv.w * (rv.w - muw) * ivw + bv.w;
    __syncthreads();
    int j = tid & 31;
    #pragma unroll
    for (int it = 0; it < 4; ++it) {
        int rown = (tid >> 5) + 8 * it;
        float acc = 0.f;
        #pragma unroll
        for (int k = 0; k < DF; ++k) acc += h[rown][k] * w[k][j];
        p[(blockIdx.x * 32 + rown) * DF + j] = acc;
    }
}

// agg (float4 gather) + MLP-2 + relu + BN-sum atomics.  32 nodes/block.
__global__ __launch_bounds__(256) void k_agg(const float* __restrict__ p,
                                             const int* __restrict__ row_ptr,
                                             const int* __restrict__ col,
                                             const float* __restrict__ b1,
                                             const float* __restrict__ w2_,
                                             const float* __restrict__ b2,
                                             float* __restrict__ r,
                                             float* __restrict__ statsL) {
    __shared__ float w[DF][DF];
    __shared__ float a[32][DF + 1];
    __shared__ float red[4][2][DF];
    int tid = threadIdx.x;
    for (int i = tid; i < DF * DF; i += 256) w[i >> 5][i & 31] = w2_[i];
    int grp = tid >> 3, c = tid & 7;
    int node = blockIdx.x * 32 + grp;
    const float4* p4 = (const float4*)p;
    float4 acc = p4[node * 8 + c];         // self term
    int e0 = row_ptr[node], e1 = row_ptr[node + 1];
    for (int e = e0; e < e1; ++e) {
        int srcn = col[e];
        float4 v = p4[srcn * 8 + c];
        acc.x += v.x; acc.y += v.y; acc.z += v.z; acc.w += v.w;
    }
    float4 b1v = ((const float4*)b1)[c];
    a[grp][4 * c + 0] = fmaxf(acc.x + b1v.x, 0.f);
    a[grp][4 * c + 1] = fmaxf(acc.y + b1v.y, 0.f);
    a[grp][4 * c + 2] = fmaxf(acc.z + b1v.z, 0.f);
    a[grp][4 * c + 3] = fmaxf(acc.w + b1v.w, 0.f);
    __syncthreads();
    int j = tid & 31;
    float b2j = b2[j];
    float s1 = 0.f, s2 = 0.f;
    #pragma unroll
    for (int it = 0; it < 4; ++it) {
        int rown = (tid >> 5) + 8 * it;
        float accm = b2j;
        #pragma unroll
        for (int k = 0; k < DF; ++k) accm += a[rown][k] * w[k][j];
        float rv = fmaxf(accm, 0.f);
        r[(blockIdx.x * 32 + rown) * DF + j] = rv;
        s1 += rv;
        s2 += rv * rv;
    }
    s1 += __shfl_down(s1, 32);
    s2 += __shfl_down(s2, 32);
    int wave = tid >> 6, lane = tid & 63;
    if (lane < 32) { red[wave][0][j] = s1; red[wave][1][j] = s2; }
    __syncthreads();
    if (tid < 32) {
        float t1 = red[0][0][j] + red[1][0][j] + red[2][0][j] + red[3][0][j];
        float t2 = red[0][1][j] + red[1][1][j] + red[2][1][j] + red[3][1][j];
        atomicAdd(&statsL[j], t1);
        atomicAdd(&statsL[DF + j], t2);
    }
}

// BN-apply (layer-5 sums) + global_add_pool; run-length accumulate over
// 8 consecutive nodes (batch is sorted) -> ~8x fewer atomics.
__global__ __launch_bounds__(256) void k_pool(const float* __restrict__ r,
                                              const float* __restrict__ statsL,
                                              const float* __restrict__ gamma,
                                              const float* __restrict__ beta,
                                              const int* __restrict__ batch,
                                              float* __restrict__ pooled) {
    int t = blockIdx.x * 256 + threadIdx.x;
    int nodeBase = (t >> 5) * 8;
    if (nodeBase >= NN) return;
    int j = t & 31;
    const float invN = 1.0f / (float)NN;
    float mu = statsL[j] * invN;
    float inv = rsqrtf(statsL[DF + j] * invN - mu * mu + BN_EPS);
    float gj = gamma[j], bj = beta[j];
    float accp = 0.f;
    int curg = batch[nodeBase];
    #pragma unroll
    for (int k = 0; k < 8; ++k) {
        int n = nodeBase + k;
        int g = batch[n];
        float val = gj * (r[n * DF + j] - mu) * inv + bj;
        if (g != curg) { atomicAdd(&pooled[curg * DF + j], accp); accp = 0.f; curg = g; }
        accp += val;
    }
    atomicAdd(&pooled[curg * DF + j], accp);
}

__global__ __launch_bounds__(128) void k_fc(const float* __restrict__ pooled,
                                            const float* __restrict__ fc_w,
                                            const float* __restrict__ fc_b,
                                            float* __restrict__ out) {
    __shared__ float pl[DF];
    int g = blockIdx.x, j = threadIdx.x;
    if (j < DF) pl[j] = pooled[g * DF + j];
    __syncthreads();
    float acc = fc_b[j];
    #pragma unroll
    for (int k = 0; k < DF; ++k) acc += pl[k] * fc_w[k * DOUT + j];
    out[g * DOUT + j] = fmaxf(acc, 0.f);
}

// ---------------------------------------------------------------- host
extern "C" void kernel_launch(void* const* d_in, const int* in_sizes, int n_in,
                              void* d_out, int out_size, void* d_ws, size_t ws_size,
                              hipStream_t stream) {
    const float* x      = (const float*)d_in[0];
    const int*   eidx   = (const int*)d_in[1];
    const int*   batch  = (const int*)d_in[2];
    const float* w1_in  = (const float*)d_in[3];
    const float* b1_in  = (const float*)d_in[4];
    const float* w1_out = (const float*)d_in[5];
    const float* b1_out = (const float*)d_in[6];
    const float* wa     = (const float*)d_in[7];
    const float* ba     = (const float*)d_in[8];
    const float* wb     = (const float*)d_in[9];
    const float* bb     = (const float*)d_in[10];
    const float* gamma  = (const float*)d_in[11];
    const float* beta   = (const float*)d_in[12];
    const float* fc_w   = (const float*)d_in[13];
    const float* fc_b   = (const float*)d_in[14];
    float* out = (float*)d_out;

    const int* esrc = eidx;
    const int* edst = eidx + EE;

    // workspace carve-up
    float* W = (float*)d_ws;
    float* p       = W;                         // NN*DF floats (pairs overlay during CSR build)
    float* r       = p + (size_t)NN * DF;       // NN*DF
    float* pooled  = r + (size_t)NN * DF;       // GG*DF
    float* stats   = pooled + (size_t)GG * DF;  // 5*64 (s1|s2 per layer)
    int* row_ptr = (int*)(stats + 5 * 64);      // NN+1
    int* col     = row_ptr + (NN + 1);          // EE
    int* hist_g  = col + EE;                    // NBUCK*SCB
    int* bbase   = hist_g + NBUCK * SCB;        // NBUCK+1
    int2* pairs  = (int2*)p;                    // EE int2 == 12.8 MB, fits in p exactly

    // ---- CSR build (bucketed; same work every call) ----
    k_bhist<<<SCB, 256, 0, stream>>>(edst, hist_g);
    k_bscan<<<1, 256, 0, stream>>>(hist_g, bbase);
    k_bscatter<<<SCB, 256, 0, stream>>>(esrc, edst, hist_g, pairs);
    k_bfill<<<NBUCK, 256, 0, stream>>>(pairs, bbase, row_ptr, col);

    hipMemsetAsync(stats, 0, sizeof(float) * 5 * 64, stream);

    // ---- layer 1 ----
    k_proj_first<<<NBLK_NODE, 256, 0, stream>>>(x, w1_in, p);
    k_agg<<<NBLK_NODE, 256, 0, stream>>>(p, row_ptr, col, b1_in, w1_out, b1_out, r, stats);

    // ---- layers 2..5 ----
    for (int i = 1; i < 5; ++i) {
        const float* w1_ = wa + (size_t)(i - 1) * DF * DF;
        const float* b1_ = ba + (size_t)(i - 1) * DF;
        const float* w2_ = wb + (size_t)(i - 1) * DF * DF;
        const float* b2_ = bb + (size_t)(i - 1) * DF;
        const float* g_  = gamma + (size_t)(i - 1) * DF;  // BN of previous layer
        const float* be_ = beta + (size_t)(i - 1) * DF;
        k_proj_hidden<<<NBLK_NODE, 256, 0, stream>>>(r, w1_, stats + (i - 1) * 64, g_, be_, p);
        k_agg<<<NBLK_NODE, 256, 0, stream>>>(p, row_ptr, col, b1_, w2_, b2_, r, stats + i * 64);
    }

    // ---- pool (+ BN of layer 5) and FC ----
    hipMemsetAsync(pooled, 0, sizeof(float) * GG * DF, stream);
    k_pool<<<((NN / 8) * 32 + 255) / 256, 256, 0, stream>>>(r, stats + 4 * 64, gamma + 4 * DF,
                                                            beta + 4 * DF, batch, pooled);
    k_fc<<<GG, 128, 0, stream>>>(pooled, fc_w, fc_b, out);
}